// Round 20
// baseline (241.802 us; speedup 1.0000x reference)
//
#include <hip/hip_runtime.h>
#include <cstddef>
#include <cstdint>

// Problem constants
static constexpr int M_ROWS  = 32768;   // B*T
static constexpr int D_INK   = 1024;
static constexpr int D_HID   = 512;
static constexpr int D_CODE_ = 256;
static constexpr int N_CODES_= 128;

// fp16 single-product pairwise-d2 gap jitter sigma ~= 0.023 -> TAU = 6.5 sigma
static constexpr float TAU_GAP = 0.15f;

using f16x8 = __attribute__((ext_vector_type(8))) _Float16;
using f32x4 = __attribute__((ext_vector_type(4))) float;
using f32x2 = __attribute__((ext_vector_type(2))) float;

__device__ __forceinline__ float rdlane(float v, int kk) {
    return __uint_as_float(__builtin_amdgcn_readlane(__float_as_uint(v), kk));
}

// ---------------------------------------------------------------------------
// Packed panel format: one panel = one (128-row tile) x (32-k step):
//   panel[(kq*128 + rc)*8 + j] = src[tile*128 + rc][ks*32 + kq*8 + j]
// 4096 x fp16 = 8 KB contiguous; frag-linear == the LDS layout the MFMA
// fragment reads want, so global->LDS DMA is fully coalesced AND linear.
// ---------------------------------------------------------------------------

__device__ __forceinline__ void dma16(const void* g, void* l) {
    __builtin_amdgcn_global_load_lds(
        (const __attribute__((address_space(1))) void*)g,
        (__attribute__((address_space(3))) void*)l, 16, 0, 0);
}

// stage one 8 KB panel into LDS: 8 dma16 instrs, 2 per wave, lane-contiguous
__device__ __forceinline__ void stage_panel(const _Float16* __restrict__ p,
                                            _Float16* dst, int w, int lane)
{
    #pragma unroll
    for (int ii = 0; ii < 2; ++ii) {
        const int I = 2 * w + ii;           // 0..7 (wave-uniform)
        dma16(p + (size_t)I * 512 + lane * 8, dst + (size_t)I * 512);
    }
}

// one BK=32 compute step: 4x4 fragment tile per wave, single fp16 product
__device__ __forceinline__ void mfma_tile(const _Float16* sA, const _Float16* sB,
                                          int wm, int wn, int kq, int lm,
                                          f32x4 (&acc)[4][4])
{
    f16x8 a[4];
    #pragma unroll
    for (int fm = 0; fm < 4; ++fm)
        a[fm] = *(const f16x8*)(sA + (kq * 128 + wm * 64 + fm * 16 + lm) * 8);
    #pragma unroll
    for (int fn = 0; fn < 4; ++fn) {
        const f16x8 b = *(const f16x8*)(sB + (kq * 128 + wn * 64 + fn * 16 + lm) * 8);
        #pragma unroll
        for (int fm = 0; fm < 4; ++fm)
            acc[fm][fn] = __builtin_amdgcn_mfma_f32_16x16x32_f16(a[fm], b, acc[fm][fn], 0, 0, 0);
    }
}

// bijective XCD swizzle (nwg % 8 == 0): consecutive logical ids -> same XCD L2
__device__ __forceinline__ int xcd_swz(int bid, int nwg) {
    const int q = nwg >> 3;
    return (bid & 7) * q + (bid >> 3);
}

// ---------------------------------------------------------------------------
// prep: codebook -> packed fp16 panels (B-side) + fp32 transposed copy
// (for coalesced fixup distance reads), exact per-code norms, zero accums.
// ---------------------------------------------------------------------------
__global__ __launch_bounds__(256)
void prep_cb_kernel(const float* __restrict__ cb, _Float16* __restrict__ cbP,
                    float* __restrict__ cbT,
                    float* __restrict__ cbnorm, float* __restrict__ accum,
                    int* __restrict__ cnt)
{
    const int j = blockIdx.x;      // code 0..127
    const int t = threadIdx.x;     // dim 0..255
    const float v = cb[j * D_CODE_ + t];
    const int ks = t >> 5, kq = (t >> 3) & 3, jj = t & 7;
    cbP[((size_t)ks * 512 + kq * 128 + j) * 8 + jj] = (_Float16)v;
    cbT[(size_t)t * N_CODES_ + j] = v;

    __shared__ float sr[256];
    sr[t] = v * v;
    __syncthreads();
    for (int s = 128; s >= 1; s >>= 1) {
        if (t < s) sr[t] += sr[t + s];
        __syncthreads();
    }
    if (t == 0) cbnorm[j] = sr[0];
    if (j == 0 && t < 2) accum[t] = 0.0f;
    if (j == 0 && t == 2) *cnt = 0;
}

// ---------------------------------------------------------------------------
// pack_w: W [K][N] fp32 -> B-side panels (n-tiles of 128, k-steps of 32).
// ---------------------------------------------------------------------------
__global__ __launch_bounds__(256)
void pack_w_kernel(const float* __restrict__ W, _Float16* __restrict__ WP,
                   int Kd, int Nd)
{
    const int ks = blockIdx.x, nt = blockIdx.y;
    const int t = threadIdx.x;
    _Float16* dst = WP + ((size_t)nt * (Kd >> 5) + ks) * 4096;
    #pragma unroll
    for (int half = 0; half < 2; ++half) {
        const int f = half * 256 + t;
        const int nc = f & 127, kq = f >> 7;
        f16x8 v;
        #pragma unroll
        for (int j = 0; j < 8; ++j)
            v[j] = (_Float16)W[(size_t)(ks * 32 + kq * 8 + j) * Nd + nt * 128 + nc];
        *(f16x8*)(dst + (size_t)f * 8) = v;
    }
}

// ---------------------------------------------------------------------------
// pack_x: x fp32 [M][1024] -> A-side fp16 panels.  Coalesced reads,
// LDS-tiled, contiguous panel writes.  grid = (M/128, 8).
// ---------------------------------------------------------------------------
__global__ __launch_bounds__(256)
void pack_x_kernel(const float* __restrict__ X, _Float16* __restrict__ XP)
{
    __shared__ _Float16 sh[128][136];   // 272 B rows: 16B-aligned frag reads
    const int t  = threadIdx.x;
    const int mt = blockIdx.x;          // m-tile
    const int kc = blockIdx.y;          // 128-wide k chunk (4 k-steps)

    const float* src = X + (size_t)mt * 128 * D_INK + kc * 128;
    #pragma unroll
    for (int i = 0; i < 16; ++i) {
        const int idx = i * 256 + t;           // 0..4095
        const int row = idx >> 5, c4 = idx & 31;
        const float4 v = *(const float4*)(src + (size_t)row * D_INK + c4 * 4);
        _Float16* d = &sh[row][c4 * 4];
        d[0] = (_Float16)v.x; d[1] = (_Float16)v.y;
        d[2] = (_Float16)v.z; d[3] = (_Float16)v.w;
    }
    __syncthreads();

    _Float16* dst = XP + ((size_t)mt * 32 + kc * 4) * 4096;
    #pragma unroll
    for (int s = 0; s < 4; ++s) {
        #pragma unroll
        for (int half = 0; half < 2; ++half) {
            const int f = half * 256 + t;
            const int rc = f & 127, kq = f >> 7;
            const f16x8 v = *(const f16x8*)(&sh[rc][s * 32 + kq * 8]);
            *(f16x8*)(dst + (size_t)s * 4096 + (size_t)f * 8) = v;
        }
    }
}

// ---------------------------------------------------------------------------
// GEMM1: h = relu(x @ W1 + b1).  All-packed-DMA staging, dbuf LDS (32 KB),
// one __syncthreads per K-step, 4 blocks/CU, XCD-swizzled n-fast grid.
// Output written directly in gemm2's packed-A layout.
// ---------------------------------------------------------------------------
__global__ __launch_bounds__(256, 4)
void gemm1_kernel(const _Float16* __restrict__ AP, const _Float16* __restrict__ BP,
                  const float* __restrict__ bias, _Float16* __restrict__ CP)
{
    __shared__ _Float16 lds[2][2][4096];   // [buf][A,B]  32 KB

    const int tid  = threadIdx.x;
    const int lane = tid & 63;
    const int w    = tid >> 6;
    const int wm = w >> 1, wn = w & 1;
    const int kq = lane >> 4, lm = lane & 15;

    const int swz = xcd_swz(blockIdx.x, (M_ROWS / 128) * (D_HID / 128));
    const int n0 = (swz & 3) * 128;
    const int m0 = (swz >> 2) * 128;

    const _Float16* Apan = AP + ((size_t)(m0 >> 7) * 32) * 4096;
    const _Float16* Bpan = BP + ((size_t)(n0 >> 7) * 32) * 4096;

    f32x4 acc[4][4] = {};

    stage_panel(Apan, &lds[0][0][0], w, lane);
    stage_panel(Bpan, &lds[0][1][0], w, lane);

    constexpr int NSTEP = D_INK / 32;
    for (int t = 0; t < NSTEP; ++t) {
        const int cur = t & 1, nxt = cur ^ 1;
        __syncthreads();               // buf[cur] staged & visible, buf[nxt] free
        if (t + 1 < NSTEP) {
            stage_panel(Apan + (size_t)(t + 1) * 4096, &lds[nxt][0][0], w, lane);
            stage_panel(Bpan + (size_t)(t + 1) * 4096, &lds[nxt][1][0], w, lane);
        }
        mfma_tile(&lds[cur][0][0], &lds[cur][1][0], wm, wn, kq, lm, acc);
    }

    // epilogue: relu; write in gemm2-packed-A layout (NT=16 over D_HID)
    #pragma unroll
    for (int fn = 0; fn < 4; ++fn) {
        const int col = n0 + wn * 64 + fn * 16 + lm;
        const float bv = bias[col];
        #pragma unroll
        for (int fm = 0; fm < 4; ++fm) {
            #pragma unroll
            for (int r = 0; r < 4; ++r) {
                const int row = m0 + wm * 64 + fm * 16 + kq * 4 + r;
                const float v = fmaxf(acc[fm][fn][r] + bv, 0.0f);
                CP[(((size_t)(row >> 7) * 16 + (col >> 5)) * 512
                    + (size_t)((col >> 3) & 3) * 128 + (row & 127)) * 8 + (col & 7)]
                    = (_Float16)v;
            }
        }
    }
}

// ---------------------------------------------------------------------------
// GEMM2: enc = h @ W2 + b2 (+ sum(enc^2) atomic).  Packed in, packed out.
// ---------------------------------------------------------------------------
__global__ __launch_bounds__(256, 4)
void gemm2_kernel(const _Float16* __restrict__ AP, const _Float16* __restrict__ BP,
                  const float* __restrict__ bias, _Float16* __restrict__ CP,
                  float* __restrict__ accum)
{
    __shared__ _Float16 lds[2][2][4096];

    const int tid  = threadIdx.x;
    const int lane = tid & 63;
    const int w    = tid >> 6;
    const int wm = w >> 1, wn = w & 1;
    const int kq = lane >> 4, lm = lane & 15;

    const int swz = xcd_swz(blockIdx.x, (M_ROWS / 128) * (D_CODE_ / 128));
    const int n0 = (swz & 1) * 128;
    const int m0 = (swz >> 1) * 128;

    const _Float16* Apan = AP + ((size_t)(m0 >> 7) * 16) * 4096;
    const _Float16* Bpan = BP + ((size_t)(n0 >> 7) * 16) * 4096;

    f32x4 acc[4][4] = {};

    stage_panel(Apan, &lds[0][0][0], w, lane);
    stage_panel(Bpan, &lds[0][1][0], w, lane);

    constexpr int NSTEP = D_HID / 32;
    for (int t = 0; t < NSTEP; ++t) {
        const int cur = t & 1, nxt = cur ^ 1;
        __syncthreads();
        if (t + 1 < NSTEP) {
            stage_panel(Apan + (size_t)(t + 1) * 4096, &lds[nxt][0][0], w, lane);
            stage_panel(Bpan + (size_t)(t + 1) * 4096, &lds[nxt][1][0], w, lane);
        }
        mfma_tile(&lds[cur][0][0], &lds[cur][1][0], wm, wn, kq, lm, acc);
    }

    float sumsq = 0.0f;
    #pragma unroll
    for (int fn = 0; fn < 4; ++fn) {
        const int col = n0 + wn * 64 + fn * 16 + lm;
        const float bv = bias[col];
        #pragma unroll
        for (int fm = 0; fm < 4; ++fm) {
            #pragma unroll
            for (int r = 0; r < 4; ++r) {
                const int row = m0 + wm * 64 + fm * 16 + kq * 4 + r;
                const float v = acc[fm][fn][r] + bv;
                sumsq = fmaf(v, v, sumsq);
                CP[(((size_t)(row >> 7) * 8 + (col >> 5)) * 512
                    + (size_t)((col >> 3) & 3) * 128 + (row & 127)) * 8 + (col & 7)]
                    = (_Float16)v;
            }
        }
    }
    #pragma unroll
    for (int mk = 1; mk <= 32; mk <<= 1) sumsq += __shfl_xor(sumsq, mk);
    if (lane == 0) atomicAdd(&accum[1], sumsq);
}

// ---------------------------------------------------------------------------
// dist: dots = enc @ cb^T (one n-block = all 128 codes); argmin epilogue
// with second-best gap flagging + min-term loss sum.
// ---------------------------------------------------------------------------
__global__ __launch_bounds__(256, 4)
void dist_kernel(const _Float16* __restrict__ AP, const _Float16* __restrict__ BP,
                 const float* __restrict__ cbn,
                 float* __restrict__ outIdx, float* __restrict__ accum,
                 int* __restrict__ cnt, int* __restrict__ list)
{
    __shared__ _Float16 lds[2][2][4096];

    const int tid  = threadIdx.x;
    const int lane = tid & 63;
    const int w    = tid >> 6;
    const int wm = w >> 1, wn = w & 1;
    const int kq = lane >> 4, lm = lane & 15;
    const int m0 = blockIdx.x * 128;

    float cbn_l[4];
    #pragma unroll
    for (int fn = 0; fn < 4; ++fn) cbn_l[fn] = cbn[wn * 64 + fn * 16 + lm];

    const _Float16* Apan = AP + ((size_t)(m0 >> 7) * 8) * 4096;

    f32x4 acc[4][4] = {};

    stage_panel(Apan, &lds[0][0][0], w, lane);
    stage_panel(BP,   &lds[0][1][0], w, lane);

    constexpr int NSTEP = D_CODE_ / 32;
    for (int t = 0; t < NSTEP; ++t) {
        const int cur = t & 1, nxt = cur ^ 1;
        __syncthreads();
        if (t + 1 < NSTEP) {
            stage_panel(Apan + (size_t)(t + 1) * 4096, &lds[nxt][0][0], w, lane);
            stage_panel(BP   + (size_t)(t + 1) * 4096, &lds[nxt][1][0], w, lane);
        }
        mfma_tile(&lds[cur][0][0], &lds[cur][1][0], wm, wn, kq, lm, acc);
    }

    __syncthreads();   // all LDS reads done before reuse as epilogue scratch
    float* eb1 = (float*)&lds[0][0][0];        // [2][128]
    float* eb2 = eb1 + 256;
    int*   eix = (int*)(eb2 + 256);

    #pragma unroll
    for (int fm = 0; fm < 4; ++fm) {
        #pragma unroll
        for (int r = 0; r < 4; ++r) {
            float b1v = 3.4e38f, b2v = 3.4e38f; int bi = 0;
            #pragma unroll
            for (int fn = 0; fn < 4; ++fn) {
                const float v = fmaf(-2.0f, acc[fm][fn][r], cbn_l[fn]);
                if (v < b1v) { b2v = b1v; b1v = v; bi = wn * 64 + fn * 16 + lm; }
                else if (v < b2v) b2v = v;
            }
            #pragma unroll
            for (int mk = 1; mk <= 8; mk <<= 1) {
                const float o1 = __shfl_xor(b1v, mk);
                const float o2 = __shfl_xor(b2v, mk);
                const int   oi = __shfl_xor(bi,  mk);
                if (o1 < b1v || (o1 == b1v && oi < bi)) { b2v = fminf(b1v, o2); b1v = o1; bi = oi; }
                else b2v = fminf(b2v, o1);
            }
            const int rl = wm * 64 + fm * 16 + kq * 4 + r;
            if (lm == 0) { eb1[wn * 128 + rl] = b1v; eb2[wn * 128 + rl] = b2v; eix[wn * 128 + rl] = bi; }
        }
    }
    __syncthreads();

    if (tid < 128) {
        const int rl = tid;
        const float a1 = eb1[rl], a2 = eb2[rl]; const int ai = eix[rl];
        const float o1 = eb1[128 + rl], o2 = eb2[128 + rl]; const int oi = eix[128 + rl];
        float B1, B2; int BI;
        if (o1 < a1 || (o1 == a1 && oi < ai)) { B1 = o1; BI = oi; B2 = fminf(a1, o2); }
        else                                  { B1 = a1; BI = ai; B2 = fminf(a2, o1); }
        outIdx[m0 + rl] = (float)BI;
        if (B2 - B1 < TAU_GAP) {
            const int p = atomicAdd(cnt, 1);
            if (p < 32768) list[p] = m0 + rl;
        }
        float s = B1;
        #pragma unroll
        for (int mk = 1; mk <= 32; mk <<= 1) s += __shfl_xor(s, mk);
        if (lane == 0) atomicAdd(&accum[0], s);
    }
}

// ---------------------------------------------------------------------------
// fixup v10: exact fp32 recompute of flagged rows, 4 rows/group, 256 threads.
// v9 engine + CROSS-BATCH double-buffered weight register rings (wvA/wvB):
// each 8-wide load batch is issued one full consume-batch ahead, so L2
// latency is paid once, not per batch.  Per-output accumulation order is
// unchanged (k-ascending single chain) -> numerics identical to v9.
// ---------------------------------------------------------------------------
__global__ __launch_bounds__(256, 4)
void fixup_kernel(const float* __restrict__ x, const float* __restrict__ W1,
                  const float* __restrict__ b1, const float* __restrict__ W2,
                  const float* __restrict__ b2, const float* __restrict__ cbT,
                  const float* __restrict__ cbnorm,
                  const int* __restrict__ cnt, const int* __restrict__ list,
                  float* __restrict__ outIdx)
{
    __shared__ float xr[4][1024];   // 16 KB
    __shared__ float hr[4][512];    //  8 KB
    __shared__ float er[4][256];    //  4 KB
    __shared__ float dv[4][128];    //  2 KB
    __shared__ int   di[4][128];    //  2 KB   -> 32 KB total

    const int tid  = threadIdx.x;
    const int lane = tid & 63;
    const int n = *cnt;
    const int ngroups = (n + 3) >> 2;

    for (int g = blockIdx.x; g < ngroups; g += gridDim.x) {
        const int base = g * 4;
        const int nr = (n - base < 4) ? (n - base) : 4;
        __syncthreads();   // LDS reuse guard across group iterations
        #pragma unroll
        for (int r = 0; r < 4; ++r) {
            if (r < nr) {
                const int row = list[base + r];
                *(float4*)&xr[r][tid * 4] =
                    *(const float4*)(x + (size_t)row * D_INK + tid * 4);
            }
        }
        __syncthreads();

        // ---- W1 phase: thread owns cols (2t, 2t+1), all 4 rows ----
        {
            const int c2 = tid * 2;
            f32x2 a01[4] = {};
            float xreg[4];
            f32x2 wvA[8], wvB[8];
            #pragma unroll
            for (int p = 0; p < 8; ++p)
                wvA[p] = *(const f32x2*)&W1[(size_t)p * D_HID + c2];
            #pragma unroll
            for (int r = 0; r < 4; ++r) xreg[r] = xr[r][lane];

            for (int kb = 0; kb < D_INK; kb += 16) {
                if (kb + 8 < D_INK) {
                    #pragma unroll
                    for (int p = 0; p < 8; ++p)
                        wvB[p] = *(const f32x2*)&W1[(size_t)(kb + 8 + p) * D_HID + c2];
                }
                #pragma unroll
                for (int p = 0; p < 8; ++p) {
                    const int kl = (kb + p) & 63;
                    #pragma unroll
                    for (int r = 0; r < 4; ++r) {
                        const float xb = rdlane(xreg[r], kl);
                        a01[r] = __builtin_elementwise_fma((f32x2){xb, xb}, wvA[p], a01[r]);
                    }
                }
                if (kb + 16 < D_INK) {
                    #pragma unroll
                    for (int p = 0; p < 8; ++p)
                        wvA[p] = *(const f32x2*)&W1[(size_t)(kb + 16 + p) * D_HID + c2];
                }
                #pragma unroll
                for (int p = 0; p < 8; ++p) {
                    const int kl = (kb + 8 + p) & 63;
                    #pragma unroll
                    for (int r = 0; r < 4; ++r) {
                        const float xb = rdlane(xreg[r], kl);
                        a01[r] = __builtin_elementwise_fma((f32x2){xb, xb}, wvB[p], a01[r]);
                    }
                }
                if (((kb + 16) & 63) == 0 && kb + 16 < D_INK) {
                    #pragma unroll
                    for (int r = 0; r < 4; ++r) xreg[r] = xr[r][kb + 16 + lane];
                }
            }
            #pragma unroll
            for (int r = 0; r < 4; ++r) {
                hr[r][c2]     = fmaxf(a01[r].x + b1[c2], 0.0f);
                hr[r][c2 + 1] = fmaxf(a01[r].y + b1[c2 + 1], 0.0f);
            }
        }
        __syncthreads();

        // ---- W2 phase: thread owns cols (cc, cc+1), rows half*2..+1 ----
        {
            const int cc = (tid & 127) * 2;
            const int half = tid >> 7;
            f32x2 a2[2] = {};
            float hreg[2];
            f32x2 wvA[8], wvB[8];
            #pragma unroll
            for (int p = 0; p < 8; ++p)
                wvA[p] = *(const f32x2*)&W2[(size_t)p * D_CODE_ + cc];
            #pragma unroll
            for (int q = 0; q < 2; ++q) hreg[q] = hr[half * 2 + q][lane];

            for (int kb = 0; kb < D_HID; kb += 16) {
                if (kb + 8 < D_HID) {
                    #pragma unroll
                    for (int p = 0; p < 8; ++p)
                        wvB[p] = *(const f32x2*)&W2[(size_t)(kb + 8 + p) * D_CODE_ + cc];
                }
                #pragma unroll
                for (int p = 0; p < 8; ++p) {
                    const int kl = (kb + p) & 63;
                    #pragma unroll
                    for (int q = 0; q < 2; ++q) {
                        const float hb = rdlane(hreg[q], kl);
                        a2[q] = __builtin_elementwise_fma((f32x2){hb, hb}, wvA[p], a2[q]);
                    }
                }
                if (kb + 16 < D_HID) {
                    #pragma unroll
                    for (int p = 0; p < 8; ++p)
                        wvA[p] = *(const f32x2*)&W2[(size_t)(kb + 16 + p) * D_CODE_ + cc];
                }
                #pragma unroll
                for (int p = 0; p < 8; ++p) {
                    const int kl = (kb + 8 + p) & 63;
                    #pragma unroll
                    for (int q = 0; q < 2; ++q) {
                        const float hb = rdlane(hreg[q], kl);
                        a2[q] = __builtin_elementwise_fma((f32x2){hb, hb}, wvB[p], a2[q]);
                    }
                }
                if (((kb + 16) & 63) == 0 && kb + 16 < D_HID) {
                    #pragma unroll
                    for (int q = 0; q < 2; ++q) hreg[q] = hr[half * 2 + q][kb + 16 + lane];
                }
            }
            #pragma unroll
            for (int q = 0; q < 2; ++q) {
                er[half * 2 + q][cc]     = a2[q].x + b2[cc];
                er[half * 2 + q][cc + 1] = a2[q].y + b2[cc + 1];
            }
        }
        __syncthreads();

        // ---- distance phase: thread owns code j, rows half*2..+1 ----
        {
            const int j = tid & 127;
            const int half = tid >> 7;
            float e2[2] = {0.0f, 0.0f}, dt[2] = {0.0f, 0.0f};
            float ereg[2];
            float cvA[8], cvB[8];
            #pragma unroll
            for (int p = 0; p < 8; ++p)
                cvA[p] = cbT[(size_t)p * N_CODES_ + j];
            #pragma unroll
            for (int q = 0; q < 2; ++q) ereg[q] = er[half * 2 + q][lane];

            for (int kb = 0; kb < D_CODE_; kb += 16) {
                if (kb + 8 < D_CODE_) {
                    #pragma unroll
                    for (int p = 0; p < 8; ++p)
                        cvB[p] = cbT[(size_t)(kb + 8 + p) * N_CODES_ + j];
                }
                #pragma unroll
                for (int p = 0; p < 8; ++p) {
                    const int kl = (kb + p) & 63;
                    #pragma unroll
                    for (int q = 0; q < 2; ++q) {
                        const float ev = rdlane(ereg[q], kl);
                        e2[q] = fmaf(ev, ev, e2[q]);
                        dt[q] = fmaf(ev, cvA[p], dt[q]);
                    }
                }
                if (kb + 16 < D_CODE_) {
                    #pragma unroll
                    for (int p = 0; p < 8; ++p)
                        cvA[p] = cbT[(size_t)(kb + 16 + p) * N_CODES_ + j];
                }
                #pragma unroll
                for (int p = 0; p < 8; ++p) {
                    const int kl = (kb + 8 + p) & 63;
                    #pragma unroll
                    for (int q = 0; q < 2; ++q) {
                        const float ev = rdlane(ereg[q], kl);
                        e2[q] = fmaf(ev, ev, e2[q]);
                        dt[q] = fmaf(ev, cvB[p], dt[q]);
                    }
                }
                if (((kb + 16) & 63) == 0 && kb + 16 < D_CODE_) {
                    #pragma unroll
                    for (int q = 0; q < 2; ++q) ereg[q] = er[half * 2 + q][kb + 16 + lane];
                }
            }
            #pragma unroll
            for (int q = 0; q < 2; ++q) {
                dv[half * 2 + q][j] = (e2[q] - 2.0f * dt[q]) + cbnorm[j];
                di[half * 2 + q][j] = j;
            }
        }
        __syncthreads();

        // ---- argmin reduce: 2 rows per pass (256 = 2 x 128), 2 passes ----
        #pragma unroll
        for (int pass = 0; pass < 2; ++pass) {
            const int r = pass * 2 + (tid >> 7);
            const int i = tid & 127;
            for (int st = 64; st >= 1; st >>= 1) {
                if (i < st) {
                    const float a = dv[r][i], b = dv[r][i + st];
                    const int  ib = di[r][i + st];
                    if (b < a || (b == a && ib < di[r][i])) { dv[r][i] = b; di[r][i] = ib; }
                }
                __syncthreads();
            }
        }
        if (tid < nr) outIdx[list[base + tid]] = (float)di[tid][0];
    }
}

// ---------------------------------------------------------------------------
__global__ void finalize_kernel(const float* __restrict__ accum, float* __restrict__ out)
{
    const float inv = 1.0f / (32768.0f * 256.0f);
    const float loss = (accum[0] + accum[1]) * inv;   // commitment == codebook
    out[32768] = loss;
    out[32769] = loss;
    out[32770] = 1.25f * loss;
}

// ---------------------------------------------------------------------------
extern "C" void kernel_launch(void* const* d_in, const int* in_sizes, int n_in,
                              void* d_out, int out_size, void* d_ws, size_t ws_size,
                              hipStream_t stream)
{
    (void)in_sizes; (void)n_in; (void)out_size; (void)ws_size;

    const float* x  = (const float*)d_in[0];  // [32768,1024]
    const float* W1 = (const float*)d_in[1];  // [1024,512]
    const float* b1 = (const float*)d_in[2];  // [512]
    const float* W2 = (const float*)d_in[3];  // [512,256]
    const float* b2 = (const float*)d_in[4];  // [256]
    const float* cb = (const float*)d_in[5];  // [128,256]
    float* out = (float*)d_out;

    // workspace layout (bytes); encP overlaps xP (xP dead after gemm1)
    char* ws = (char*)d_ws;
    _Float16* W1P  = (_Float16*)(ws + 0);                 // 1 MB   (4 nt x 32 ks)
    _Float16* W2P  = (_Float16*)(ws + 1048576);           // 256 KB (2 nt x 16 ks)
    _Float16* cbP  = (_Float16*)(ws + 1310720);           // 64 KB  (1 nt x 8 ks)
    float*    cbn  = (float*   )(ws + 1376256);           // 512 B
    float*    accum= (float*   )(ws + 1376768);           // 64 B
    int*      cnt  = (int*     )(ws + 1376832);           // 64 B
    int*      list = (int*     )(ws + 1376896);           // 128 KB
    float*    cbT  = (float*   )(ws + 1507968);           // 128 KB fp32 [256][128]
    _Float16* xP   = (_Float16*)(ws + (size_t)(2u<<20));              // 64 MB
    _Float16* encP = (_Float16*)(ws + (size_t)(2u<<20));              // 16 MB (reuse)
    _Float16* hP   = (_Float16*)(ws + (size_t)(2u<<20) + 67108864);   // 32 MB

    prep_cb_kernel<<<N_CODES_, 256, 0, stream>>>(cb, cbP, cbT, cbn, accum, cnt);
    pack_w_kernel<<<dim3(D_INK / 32, D_HID / 128), 256, 0, stream>>>(W1, W1P, D_INK, D_HID);
    pack_w_kernel<<<dim3(D_HID / 32, D_CODE_ / 128), 256, 0, stream>>>(W2, W2P, D_HID, D_CODE_);
    pack_x_kernel<<<dim3(M_ROWS / 128, D_INK / 128), 256, 0, stream>>>(x, xP);

    gemm1_kernel<<<(M_ROWS / 128) * (D_HID / 128), 256, 0, stream>>>(xP, W1P, b1, hP);
    gemm2_kernel<<<(M_ROWS / 128) * (D_CODE_ / 128), 256, 0, stream>>>(hP, W2P, b2, encP, accum);
    dist_kernel<<<M_ROWS / 128, 256, 0, stream>>>(encP, cbP, cbn, out, accum, cnt, list);
    fixup_kernel<<<1024, 256, 0, stream>>>(x, W1, b1, W2, b2, cbT, cbn, cnt, list, out);
    finalize_kernel<<<1, 1, 0, stream>>>(accum, out);
}